// Round 7
// baseline (208.504 us; speedup 1.0000x reference)
//
#include <hip/hip_runtime.h>
#include <cmath>
#include <stdint.h>

#define DEV __device__ __forceinline__

typedef float v2f __attribute__((ext_vector_type(2)));

static DEV float fast_exp2(float x) { return __builtin_amdgcn_exp2f(x); }
static DEV float fast_rcp(float x) { return __builtin_amdgcn_rcpf(x); }

#define LOG2E 1.4426950408889634f

static DEV float rdl(float x, int l) {
  return __int_as_float(__builtin_amdgcn_readlane(__float_as_int(x), l));
}

// packed fp32 FMA: acc.{lo,hi} += w.{lo,hi} * h.{lo,hi} (all VGPR)
static DEV void pkfma(v2f& acc, v2f w, v2f h) {
  asm("v_pk_fma_f32 %0, %1, %2, %0" : "+v"(acc) : "v"(w), "v"(h));
}

// wave-wide broadcast of lane (byteidx>>2)'s value via LDS-pipe bpermute
// (uniform address -> no bank conflict; off the VALU pipe)
static DEV float bcast(int byteidx, float v) {
  return __int_as_float(__builtin_amdgcn_ds_bpermute(byteidx, __float_as_int(v)));
}

// broadcast the value held by lane (4j+K) to all lanes of quad j (DPP quad_perm)
template <int K>
static DEV float qb(float x) {
  return __int_as_float(
      __builtin_amdgcn_update_dpp(0, __float_as_int(x), K * 0x55, 0xF, 0xF, true));
}

// m = max(m, dpp_shift(m)); bound_ctrl=true -> invalid lanes read 0.0f,
// safe as identity since all our probabilities are >= 0.
template <int CTRL>
static DEV float dppmax(float x) {
  float o = __int_as_float(
      __builtin_amdgcn_update_dpp(0, __float_as_int(x), CTRL, 0xF, 0xF, true));
  return fmaxf(x, o);
}

// full wave64 max via DPP (VALU only): row_shr 1,2,4,8 then row_bcast15/31.
static DEV float wavemax_bcast(float m) {
  m = dppmax<0x111>(m);
  m = dppmax<0x112>(m);
  m = dppmax<0x114>(m);
  m = dppmax<0x118>(m);
  m = dppmax<0x142>(m);  // row_bcast:15
  m = dppmax<0x143>(m);  // row_bcast:31
  return rdl(m, 63);
}

struct KP {
  const float* tags; const float* lem;
  const float* eWih0; const float* eWhh0; const float* ebih0; const float* ebhh0;
  const float* eWih1; const float* eWhh1; const float* ebih1; const float* ebhh1;
  const float* eWih2; const float* eWhh2; const float* ebih2; const float* ebhh2;
  const float* dWih0; const float* dWhh0; const float* dbih0; const float* dbhh0;
  const float* dWih1; const float* dWhh1; const float* dbih1; const float* dbhh1;
  const float* dWih2; const float* dWhh2; const float* dbih2; const float* dbhh2;
  const float* linW; const float* linb;
  float* outp; float* outt;
  int B;
};

// One wave (64 lanes) per batch chain. 4 chains per 256-thread block.
// lane = 4*j + k : lane owns gate row (k*10 + j); k: 0=i, 1=f, 2=g~, 3=o.
// Lanes 40..63 (j>=10) are clamped to j=9 and compute harmless duplicates.
// Dots use v_pk_fma_f32; h replicated as packed v2f pairs via ds_bpermute
// (LDS pipe) instead of v_readlane (VALU pipe). Linear weights live in LDS.
// NOTE: no min-occupancy pin — __launch_bounds__(256,4) forced a 64-VGPR cap
// and spilled the loop state to scratch (R6: FETCH 1.9->48MB, WRITE 97->189MB).
__global__ __launch_bounds__(256) void seq2seq_kernel(KP P) {
  const int tid = threadIdx.x;
  const int lane = tid & 63;
  const int b = blockIdx.x * 4 + (tid >> 6);

  // --- stage linW into LDS verbatim (row-major 100x10, stride 40B) ---
  __shared__ float slin[1000];
  for (int i = tid; i < 1000; i += 256) slin[i] = P.linW[i];
  __syncthreads();
  if (b >= P.B) return;

  const int jq = lane >> 2;
  const int kg = lane & 3;
  const int jj = (jq < 10) ? jq : 9;
  const int row = kg * 10 + jj;

  // unified activation: sigmoid for i,f,o; tanh (=2*sigmoid(2x)-1) for g~
  const float kc = (kg == 2) ? (-2.0f * LOG2E) : (-LOG2E);
  const float am = (kg == 2) ? 2.0f : 1.0f;
  const float ab = (kg == 2) ? -1.0f : 0.0f;

  auto act = [&](float g) -> float {
    float y = fast_rcp(1.0f + fast_exp2(g * kc));
    return fmaf(am, y, ab);
  };

  // per-chain uniform data
  float tv = (lane < 63) ? P.tags[(size_t)b * 63 + lane] : 0.0f;
  float lemv = (lane < 32) ? P.lem[(size_t)b * 32 + lane] : 0.0f;

  // --- fold the (time-constant) tag contribution into the layer-0 biases ---
  float pre0 = P.ebih0[row] + P.ebhh0[row];
  float dpre0 = P.dbih0[row] + P.dbhh0[row];
  float ew0c, dw0c;
  {
    const float4* e4 = (const float4*)P.eWih0 + row * 16;
    const float4* d4 = (const float4*)P.dWih0 + row * 16;
    float4 we = e4[0], wd = d4[0];
    ew0c = we.x; dw0c = wd.x;
    float t0 = rdl(tv, 0), t1 = rdl(tv, 1), t2 = rdl(tv, 2);
    pre0 = fmaf(we.y, t0, pre0); pre0 = fmaf(we.z, t1, pre0); pre0 = fmaf(we.w, t2, pre0);
    dpre0 = fmaf(wd.y, t0, dpre0); dpre0 = fmaf(wd.z, t1, dpre0); dpre0 = fmaf(wd.w, t2, dpre0);
#pragma unroll
    for (int c = 1; c < 16; c++) {
      float4 e = e4[c], d = d4[c];
      int dd = 4 * c - 1;
      float u0 = rdl(tv, dd), u1 = rdl(tv, dd + 1), u2 = rdl(tv, dd + 2), u3 = rdl(tv, dd + 3);
      pre0 = fmaf(e.x, u0, pre0); pre0 = fmaf(e.y, u1, pre0);
      pre0 = fmaf(e.z, u2, pre0); pre0 = fmaf(e.w, u3, pre0);
      dpre0 = fmaf(d.x, u0, dpre0); dpre0 = fmaf(d.y, u1, dpre0);
      dpre0 = fmaf(d.z, u2, dpre0); dpre0 = fmaf(d.w, u3, dpre0);
    }
  }

  // --- encoder weights as VGPR pairs (lane holds its gate row, 5 v2f each) ---
  v2f ehh0[5], eih1[5], ehh1[5], eih2[5], ehh2[5];
  {
    const v2f* a0 = (const v2f*)(P.eWhh0 + row * 10);
    const v2f* a1 = (const v2f*)(P.eWih1 + row * 10);
    const v2f* a2 = (const v2f*)(P.eWhh1 + row * 10);
    const v2f* a3 = (const v2f*)(P.eWih2 + row * 10);
    const v2f* a4 = (const v2f*)(P.eWhh2 + row * 10);
#pragma unroll
    for (int q = 0; q < 5; q++) {
      ehh0[q] = a0[q]; eih1[q] = a1[q]; ehh1[q] = a2[q];
      eih2[q] = a3[q]; ehh2[q] = a4[q];
    }
  }
  float pre1 = P.ebih1[row] + P.ebhh1[row];
  float pre2 = P.ebih2[row] + P.ebhh2[row];

  // state: h replicated as packed v2f pairs {h_{2q}, h_{2q+1}}; c per-quad
  v2f h0[5], h1[5], h2[5];
#pragma unroll
  for (int q = 0; q < 5; q++) { h0[q] = v2f{0, 0}; h1[q] = v2f{0, 0}; h2[q] = v2f{0, 0}; }
  float c0 = 0.0f, c1 = 0.0f, c2 = 0.0f;

  // h_j computed (quad-uniform) on quad j; pair q = lanes 8q, 8q+4
  auto upd = [&](float a, float& c, v2f (&h)[5]) {
    float a0 = qb<0>(a);  // sigmoid(i)
    float a1 = qb<1>(a);  // sigmoid(f)
    float a2 = qb<2>(a);  // tanh(g~)
    float a3 = qb<3>(a);  // sigmoid(o)
    c = fmaf(a1, c, a0 * a2);
    // tanh(c) = 2*sigmoid(2c)-1; exp2 over/underflow saturates correctly
    float y = fast_rcp(1.0f + fast_exp2(c * (-2.0f * LOG2E)));
    float hv = a3 * fmaf(2.0f, y, -1.0f);
#pragma unroll
    for (int q = 0; q < 5; q++) {
      h[q].x = bcast(32 * q, hv);
      h[q].y = bcast(32 * q + 16, hv);
    }
  };

  auto step = [&](float x, const v2f (&wh0)[5], const v2f (&wi1)[5],
                  const v2f (&wh1)[5], const v2f (&wi2)[5], const v2f (&wh2)[5],
                  float w0c, float p0_, float p1_, float p2_) {
    v2f a{fmaf(w0c, x, p0_), 0.0f};
#pragma unroll
    for (int q = 0; q < 5; q++) pkfma(a, wh0[q], h0[q]);
    upd(act(a.x + a.y), c0, h0);

    v2f aa{p1_, 0.0f}, bb{0.0f, 0.0f};
#pragma unroll
    for (int q = 0; q < 5; q++) { pkfma(aa, wi1[q], h0[q]); pkfma(bb, wh1[q], h1[q]); }
    upd(act((aa.x + aa.y) + (bb.x + bb.y)), c1, h1);

    v2f cc_{p2_, 0.0f}, dd{0.0f, 0.0f};
#pragma unroll
    for (int q = 0; q < 5; q++) { pkfma(cc_, wi2[q], h1[q]); pkfma(dd, wh2[q], h2[q]); }
    upd(act((cc_.x + cc_.y) + (dd.x + dd.y)), c2, h2);
  };

  // ---------------- encoder: 32 steps ----------------
  for (int t = 0; t < 32; t++) {
    step(rdl(lemv, t), ehh0, eih1, ehh1, eih2, ehh2, ew0c, pre0, pre1, pre2);
  }

  // --- decoder weights overwrite the same registers (no extra pressure) ---
  {
    const v2f* a0 = (const v2f*)(P.dWhh0 + row * 10);
    const v2f* a1 = (const v2f*)(P.dWih1 + row * 10);
    const v2f* a2 = (const v2f*)(P.dWhh1 + row * 10);
    const v2f* a3 = (const v2f*)(P.dWih2 + row * 10);
    const v2f* a4 = (const v2f*)(P.dWhh2 + row * 10);
#pragma unroll
    for (int q = 0; q < 5; q++) {
      ehh0[q] = a0[q]; eih1[q] = a1[q]; ehh1[q] = a2[q];
      eih2[q] = a3[q]; ehh2[q] = a4[q];
    }
  }
  pre1 = P.dbih1[row] + P.dbhh1[row];
  pre2 = P.dbih2[row] + P.dbhh2[row];

  // linear layer: lane owns rows lane and (64+lane if lane<36); W from LDS
  const int lr2 = (lane < 36) ? (64 + lane) : 99;
  const v2f* lp0 = (const v2f*)(slin + lane * 10);
  const v2f* lp1 = (const v2f*)(slin + lr2 * 10);
  float lb0 = P.linb[lane];
  float lb1 = (lane < 36) ? P.linb[lr2] : -1e30f;

  float* op0 = P.outp + (size_t)b * 3000;
  float tok = 1.0f;   // START
  float tokv = 0.0f;  // lane s accumulates step-s token

  // ---------------- decoder: 30 steps ----------------
  for (int s = 0; s < 30; s++) {
    step(tok, ehh0, eih1, ehh1, eih2, ehh2, dw0c, dpre0, pre1, pre2);

    // linear + sigmoid (packed dots, weights streamed from LDS)
    v2f za{lb0, 0.0f}, zb{lb1, 0.0f};
#pragma unroll
    for (int q = 0; q < 5; q++) { pkfma(za, lp0[q], h2[q]); pkfma(zb, lp1[q], h2[q]); }
    float z0 = za.x + za.y, z1 = zb.x + zb.y;
    float p0 = fast_rcp(1.0f + fast_exp2(z0 * (-LOG2E)));
    float p1 = fast_rcp(1.0f + fast_exp2(z1 * (-LOG2E)));  // lanes>=36: exactly 0

    float* op = op0 + s * 100;
    op[lane] = p0;
    if (lane < 36) op[64 + lane] = p1;

    // argmax, first-occurrence: DPP wave-max (VALU) + ballot/ctz (SALU).
    float vm = wavemax_bcast(fmaxf(p0, p1));
    unsigned long long m0 = __ballot(p0 == vm);
    unsigned long long m1 = __ballot(p1 == vm);
    int im = m0 ? (int)__builtin_ctzll(m0) : 64 + (int)__builtin_ctzll(m1);
    tok = (float)im;
    tokv = (lane == s) ? tok : tokv;
  }

  if (lane < 30) P.outt[(size_t)b * 30 + lane] = tokv;
}

extern "C" void kernel_launch(void* const* d_in, const int* in_sizes, int n_in,
                              void* d_out, int out_size, void* d_ws, size_t ws_size,
                              hipStream_t stream) {
  KP P;
  P.tags = (const float*)d_in[2];
  P.lem = (const float*)d_in[3];
  P.eWih0 = (const float*)d_in[4];  P.eWhh0 = (const float*)d_in[5];
  P.ebih0 = (const float*)d_in[6];  P.ebhh0 = (const float*)d_in[7];
  P.eWih1 = (const float*)d_in[8];  P.eWhh1 = (const float*)d_in[9];
  P.ebih1 = (const float*)d_in[10]; P.ebhh1 = (const float*)d_in[11];
  P.eWih2 = (const float*)d_in[12]; P.eWhh2 = (const float*)d_in[13];
  P.ebih2 = (const float*)d_in[14]; P.ebhh2 = (const float*)d_in[15];
  P.dWih0 = (const float*)d_in[16]; P.dWhh0 = (const float*)d_in[17];
  P.dbih0 = (const float*)d_in[18]; P.dbhh0 = (const float*)d_in[19];
  P.dWih1 = (const float*)d_in[20]; P.dWhh1 = (const float*)d_in[21];
  P.dbih1 = (const float*)d_in[22]; P.dbhh1 = (const float*)d_in[23];
  P.dWih2 = (const float*)d_in[24]; P.dWhh2 = (const float*)d_in[25];
  P.dbih2 = (const float*)d_in[26]; P.dbhh2 = (const float*)d_in[27];
  P.linW = (const float*)d_in[28];
  P.linb = (const float*)d_in[29];

  const int B = in_sizes[3] / 32;  // lemmata is (B, 32)
  P.B = B;
  P.outp = (float*)d_out;
  P.outt = P.outp + (size_t)B * 3000;

  const int blocks = (B + 3) / 4;  // 4 chains (waves) per 256-thread block
  seq2seq_kernel<<<dim3(blocks), dim3(256), 0, stream>>>(P);
}

// Round 8
// 157.659 us; speedup vs baseline: 1.3225x; 1.3225x over previous
//
#include <hip/hip_runtime.h>
#include <cmath>
#include <stdint.h>

#define DEV __device__ __forceinline__

typedef float v2f __attribute__((ext_vector_type(2)));

static DEV float fast_exp2(float x) { return __builtin_amdgcn_exp2f(x); }
static DEV float fast_rcp(float x) { return __builtin_amdgcn_rcpf(x); }

#define LOG2E 1.4426950408889634f

static DEV float rdl(float x, int l) {
  return __int_as_float(__builtin_amdgcn_readlane(__float_as_int(x), l));
}
static DEV int rdli(float x, int l) {
  return __builtin_amdgcn_readlane(__float_as_int(x), l);
}
// pack two wave-uniform floats into one 64-bit scalar (SALU, off the VALU pipe)
static DEV uint64_t pack2(int lo, int hi) {
  return ((uint64_t)(uint32_t)hi << 32) | (uint32_t)lo;
}

// packed fp32 FMA: acc.{lo,hi} += w.{lo,hi} * h.{lo,hi}; h is an SGPR pair.
static DEV void pkfma(v2f& acc, v2f w, uint64_t h) {
  asm("v_pk_fma_f32 %0, %1, %2, %0" : "+v"(acc) : "v"(w), "s"(h));
}

// broadcast the value held by lane (4j+K) to all lanes of quad j (DPP quad_perm)
template <int K>
static DEV float qb(float x) {
  return __int_as_float(
      __builtin_amdgcn_update_dpp(0, __float_as_int(x), K * 0x55, 0xF, 0xF, true));
}

// m = max(m, dpp_shift(m)); bound_ctrl=true -> invalid lanes read 0.0f,
// safe as identity since all our probabilities are >= 0.
template <int CTRL>
static DEV float dppmax(float x) {
  float o = __int_as_float(
      __builtin_amdgcn_update_dpp(0, __float_as_int(x), CTRL, 0xF, 0xF, true));
  return fmaxf(x, o);
}

// full wave64 max via DPP (VALU only): row_shr 1,2,4,8 then row_bcast15/31.
static DEV float wavemax_bcast(float m) {
  m = dppmax<0x111>(m);
  m = dppmax<0x112>(m);
  m = dppmax<0x114>(m);
  m = dppmax<0x118>(m);
  m = dppmax<0x142>(m);  // row_bcast:15
  m = dppmax<0x143>(m);  // row_bcast:31
  return rdl(m, 63);
}

struct KP {
  const float* tags; const float* lem;
  const float* eWih0; const float* eWhh0; const float* ebih0; const float* ebhh0;
  const float* eWih1; const float* eWhh1; const float* ebih1; const float* ebhh1;
  const float* eWih2; const float* eWhh2; const float* ebih2; const float* ebhh2;
  const float* dWih0; const float* dWhh0; const float* dbih0; const float* dbhh0;
  const float* dWih1; const float* dWhh1; const float* dbih1; const float* dbhh1;
  const float* dWih2; const float* dWhh2; const float* dbih2; const float* dbhh2;
  const float* linW; const float* linb;
  float* outp; float* outt;
  int B;
};

// One wave (64 lanes) per batch chain. 4 chains per 256-thread block.
// lane = 4*j + k : lane owns gate row (k*10 + j); k: 0=i, 1=f, 2=g~, 3=o.
// Lanes 40..63 (j>=10) are clamped to j=9 and compute harmless duplicates.
// Dots use v_pk_fma_f32: weights in VGPR pairs, h replicated as SGPR 64-bit
// pairs (R5 structure — best measured). Decoder linear weights live in LDS to
// push VGPR count to the <=64 occupancy class (R5 was 84 with lw in regs).
// NOTE: no min-occupancy pin — __launch_bounds__(256,4) caused a 64-VGPR cap
// WITH the register-resident linW and spilled to scratch (R6 post-mortem).
__global__ __launch_bounds__(256) void seq2seq_kernel(KP P) {
  const int tid = threadIdx.x;
  const int lane = tid & 63;
  const int b = blockIdx.x * 4 + (tid >> 6);

  // --- stage linW into LDS verbatim (row-major 100x10, 40 B rows) ---
  __shared__ float slin[1000];
  for (int i = tid; i < 1000; i += 256) slin[i] = P.linW[i];
  __syncthreads();
  if (b >= P.B) return;

  const int jq = lane >> 2;
  const int kg = lane & 3;
  const int jj = (jq < 10) ? jq : 9;
  const int row = kg * 10 + jj;

  // unified activation: sigmoid for i,f,o; tanh (=2*sigmoid(2x)-1) for g~
  const float kc = (kg == 2) ? (-2.0f * LOG2E) : (-LOG2E);
  const float am = (kg == 2) ? 2.0f : 1.0f;
  const float ab = (kg == 2) ? -1.0f : 0.0f;

  auto act = [&](float g) -> float {
    float y = fast_rcp(1.0f + fast_exp2(g * kc));
    return fmaf(am, y, ab);
  };

  // per-chain uniform data
  float tv = (lane < 63) ? P.tags[(size_t)b * 63 + lane] : 0.0f;
  float lemv = (lane < 32) ? P.lem[(size_t)b * 32 + lane] : 0.0f;

  // --- fold the (time-constant) tag contribution into the layer-0 biases ---
  float pre0 = P.ebih0[row] + P.ebhh0[row];
  float dpre0 = P.dbih0[row] + P.dbhh0[row];
  float ew0c, dw0c;
  {
    const float4* e4 = (const float4*)P.eWih0 + row * 16;
    const float4* d4 = (const float4*)P.dWih0 + row * 16;
    float4 we = e4[0], wd = d4[0];
    ew0c = we.x; dw0c = wd.x;
    float t0 = rdl(tv, 0), t1 = rdl(tv, 1), t2 = rdl(tv, 2);
    pre0 = fmaf(we.y, t0, pre0); pre0 = fmaf(we.z, t1, pre0); pre0 = fmaf(we.w, t2, pre0);
    dpre0 = fmaf(wd.y, t0, dpre0); dpre0 = fmaf(wd.z, t1, dpre0); dpre0 = fmaf(wd.w, t2, dpre0);
#pragma unroll
    for (int c = 1; c < 16; c++) {
      float4 e = e4[c], d = d4[c];
      int dd = 4 * c - 1;
      float u0 = rdl(tv, dd), u1 = rdl(tv, dd + 1), u2 = rdl(tv, dd + 2), u3 = rdl(tv, dd + 3);
      pre0 = fmaf(e.x, u0, pre0); pre0 = fmaf(e.y, u1, pre0);
      pre0 = fmaf(e.z, u2, pre0); pre0 = fmaf(e.w, u3, pre0);
      dpre0 = fmaf(d.x, u0, dpre0); dpre0 = fmaf(d.y, u1, dpre0);
      dpre0 = fmaf(d.z, u2, dpre0); dpre0 = fmaf(d.w, u3, dpre0);
    }
  }

  // --- encoder weights as VGPR pairs (lane holds its gate row, 5 v2f each) ---
  v2f ehh0[5], eih1[5], ehh1[5], eih2[5], ehh2[5];
  {
    const v2f* a0 = (const v2f*)(P.eWhh0 + row * 10);
    const v2f* a1 = (const v2f*)(P.eWih1 + row * 10);
    const v2f* a2 = (const v2f*)(P.eWhh1 + row * 10);
    const v2f* a3 = (const v2f*)(P.eWih2 + row * 10);
    const v2f* a4 = (const v2f*)(P.eWhh2 + row * 10);
#pragma unroll
    for (int q = 0; q < 5; q++) {
      ehh0[q] = a0[q]; eih1[q] = a1[q]; ehh1[q] = a2[q];
      eih2[q] = a3[q]; ehh2[q] = a4[q];
    }
  }
  float pre1 = P.ebih1[row] + P.ebhh1[row];
  float pre2 = P.ebih2[row] + P.ebhh2[row];

  // state: h replicated as SGPR pairs {h_{2q}, h_{2q+1}}; c lives per-quad
  uint64_t h0[5], h1[5], h2[5];
#pragma unroll
  for (int q = 0; q < 5; q++) { h0[q] = 0; h1[q] = 0; h2[q] = 0; }
  float c0 = 0.0f, c1 = 0.0f, c2 = 0.0f;

  auto upd = [&](float a, float& c, uint64_t (&h)[5]) {
    float a0 = qb<0>(a);  // sigmoid(i)
    float a1 = qb<1>(a);  // sigmoid(f)
    float a2 = qb<2>(a);  // tanh(g~)
    float a3 = qb<3>(a);  // sigmoid(o)
    c = fmaf(a1, c, a0 * a2);
    // tanh(c) = 2*sigmoid(2c)-1; exp2 over/underflow saturates correctly
    float y = fast_rcp(1.0f + fast_exp2(c * (-2.0f * LOG2E)));
    float hv = a3 * fmaf(2.0f, y, -1.0f);
#pragma unroll
    for (int q = 0; q < 5; q++) h[q] = pack2(rdli(hv, 8 * q), rdli(hv, 8 * q + 4));
  };

  auto step = [&](float x, const v2f (&wh0)[5], const v2f (&wi1)[5],
                  const v2f (&wh1)[5], const v2f (&wi2)[5], const v2f (&wh2)[5],
                  float w0c, float p0_, float p1_, float p2_) {
    v2f a{fmaf(w0c, x, p0_), 0.0f};
#pragma unroll
    for (int q = 0; q < 5; q++) pkfma(a, wh0[q], h0[q]);
    upd(act(a.x + a.y), c0, h0);

    v2f aa{p1_, 0.0f}, bb{0.0f, 0.0f};
#pragma unroll
    for (int q = 0; q < 5; q++) { pkfma(aa, wi1[q], h0[q]); pkfma(bb, wh1[q], h1[q]); }
    upd(act((aa.x + aa.y) + (bb.x + bb.y)), c1, h1);

    v2f cc_{p2_, 0.0f}, dd{0.0f, 0.0f};
#pragma unroll
    for (int q = 0; q < 5; q++) { pkfma(cc_, wi2[q], h1[q]); pkfma(dd, wh2[q], h2[q]); }
    upd(act((cc_.x + cc_.y) + (dd.x + dd.y)), c2, h2);
  };

  // ---------------- encoder: 32 steps ----------------
  for (int t = 0; t < 32; t++) {
    step(rdl(lemv, t), ehh0, eih1, ehh1, eih2, ehh2, ew0c, pre0, pre1, pre2);
  }

  // --- decoder weights overwrite the same registers (no extra pressure) ---
  {
    const v2f* a0 = (const v2f*)(P.dWhh0 + row * 10);
    const v2f* a1 = (const v2f*)(P.dWih1 + row * 10);
    const v2f* a2 = (const v2f*)(P.dWhh1 + row * 10);
    const v2f* a3 = (const v2f*)(P.dWih2 + row * 10);
    const v2f* a4 = (const v2f*)(P.dWhh2 + row * 10);
#pragma unroll
    for (int q = 0; q < 5; q++) {
      ehh0[q] = a0[q]; eih1[q] = a1[q]; ehh1[q] = a2[q];
      eih2[q] = a3[q]; ehh2[q] = a4[q];
    }
  }
  pre1 = P.dbih1[row] + P.dbhh1[row];
  pre2 = P.dbih2[row] + P.dbhh2[row];

  // linear layer: lane owns rows lane and (64+lane if lane<36); W from LDS
  const int lr2 = (lane < 36) ? (64 + lane) : 99;
  const v2f* lp0 = (const v2f*)(slin + lane * 10);
  const v2f* lp1 = (const v2f*)(slin + lr2 * 10);
  float lb0 = P.linb[lane];
  float lb1 = (lane < 36) ? P.linb[lr2] : -1e30f;

  float* op0 = P.outp + (size_t)b * 3000;
  float tok = 1.0f;   // START
  float tokv = 0.0f;  // lane s accumulates step-s token

  // ---------------- decoder: 30 steps ----------------
  for (int s = 0; s < 30; s++) {
    step(tok, ehh0, eih1, ehh1, eih2, ehh2, dw0c, dpre0, pre1, pre2);

    // linear + sigmoid (packed dots, weights streamed from LDS)
    v2f za{lb0, 0.0f}, zb{lb1, 0.0f};
#pragma unroll
    for (int q = 0; q < 5; q++) { pkfma(za, lp0[q], h2[q]); pkfma(zb, lp1[q], h2[q]); }
    float z0 = za.x + za.y, z1 = zb.x + zb.y;
    float p0 = fast_rcp(1.0f + fast_exp2(z0 * (-LOG2E)));
    float p1 = fast_rcp(1.0f + fast_exp2(z1 * (-LOG2E)));  // lanes>=36: exactly 0

    float* op = op0 + s * 100;
    op[lane] = p0;
    if (lane < 36) op[64 + lane] = p1;

    // argmax, first-occurrence: DPP wave-max (VALU) + ballot/ctz (SALU).
    // fmax returns one of its inputs bitwise, so vm matches some p exactly.
    float vm = wavemax_bcast(fmaxf(p0, p1));
    unsigned long long m0 = __ballot(p0 == vm);
    unsigned long long m1 = __ballot(p1 == vm);
    int im = m0 ? (int)__builtin_ctzll(m0) : 64 + (int)__builtin_ctzll(m1);
    tok = (float)im;
    tokv = (lane == s) ? tok : tokv;
  }

  if (lane < 30) P.outt[(size_t)b * 30 + lane] = tokv;
}

extern "C" void kernel_launch(void* const* d_in, const int* in_sizes, int n_in,
                              void* d_out, int out_size, void* d_ws, size_t ws_size,
                              hipStream_t stream) {
  KP P;
  P.tags = (const float*)d_in[2];
  P.lem = (const float*)d_in[3];
  P.eWih0 = (const float*)d_in[4];  P.eWhh0 = (const float*)d_in[5];
  P.ebih0 = (const float*)d_in[6];  P.ebhh0 = (const float*)d_in[7];
  P.eWih1 = (const float*)d_in[8];  P.eWhh1 = (const float*)d_in[9];
  P.ebih1 = (const float*)d_in[10]; P.ebhh1 = (const float*)d_in[11];
  P.eWih2 = (const float*)d_in[12]; P.eWhh2 = (const float*)d_in[13];
  P.ebih2 = (const float*)d_in[14]; P.ebhh2 = (const float*)d_in[15];
  P.dWih0 = (const float*)d_in[16]; P.dWhh0 = (const float*)d_in[17];
  P.dbih0 = (const float*)d_in[18]; P.dbhh0 = (const float*)d_in[19];
  P.dWih1 = (const float*)d_in[20]; P.dWhh1 = (const float*)d_in[21];
  P.dbih1 = (const float*)d_in[22]; P.dbhh1 = (const float*)d_in[23];
  P.dWih2 = (const float*)d_in[24]; P.dWhh2 = (const float*)d_in[25];
  P.dbih2 = (const float*)d_in[26]; P.dbhh2 = (const float*)d_in[27];
  P.linW = (const float*)d_in[28];
  P.linb = (const float*)d_in[29];

  const int B = in_sizes[3] / 32;  // lemmata is (B, 32)
  P.B = B;
  P.outp = (float*)d_out;
  P.outt = P.outp + (size_t)B * 3000;

  const int blocks = (B + 3) / 4;  // 4 chains (waves) per 256-thread block
  seq2seq_kernel<<<dim3(blocks), dim3(256), 0, stream>>>(P);
}

// Round 9
// 150.327 us; speedup vs baseline: 1.3870x; 1.0488x over previous
//
#include <hip/hip_runtime.h>
#include <cmath>
#include <stdint.h>

#define DEV __device__ __forceinline__

typedef float v2f __attribute__((ext_vector_type(2)));

static DEV float fast_exp2(float x) { return __builtin_amdgcn_exp2f(x); }
static DEV float fast_rcp(float x) { return __builtin_amdgcn_rcpf(x); }

#define LOG2E 1.4426950408889634f

static DEV float rdl(float x, int l) {
  return __int_as_float(__builtin_amdgcn_readlane(__float_as_int(x), l));
}
static DEV int rdli(float x, int l) {
  return __builtin_amdgcn_readlane(__float_as_int(x), l);
}
// pack two wave-uniform floats into one 64-bit scalar (SALU, off the VALU pipe)
static DEV uint64_t pack2(int lo, int hi) {
  return ((uint64_t)(uint32_t)hi << 32) | (uint32_t)lo;
}

// packed fp32 FMA: acc.{lo,hi} += w.{lo,hi} * h.{lo,hi}; h is an SGPR pair.
static DEV void pkfma(v2f& acc, v2f w, uint64_t h) {
  asm("v_pk_fma_f32 %0, %1, %2, %0" : "+v"(acc) : "v"(w), "s"(h));
}

// broadcast the value held by lane (4j+K) to all lanes of quad j (DPP quad_perm)
template <int K>
static DEV float qb(float x) {
  return __int_as_float(
      __builtin_amdgcn_update_dpp(0, __float_as_int(x), K * 0x55, 0xF, 0xF, true));
}

// m = max(m, dpp_shift(m)); bound_ctrl=true -> invalid lanes read 0.0f,
// safe as identity since all our probabilities are >= 0.
template <int CTRL>
static DEV float dppmax(float x) {
  float o = __int_as_float(
      __builtin_amdgcn_update_dpp(0, __float_as_int(x), CTRL, 0xF, 0xF, true));
  return fmaxf(x, o);
}

// full wave64 max via DPP (VALU only): row_shr 1,2,4,8 then row_bcast15/31.
static DEV float wavemax_bcast(float m) {
  m = dppmax<0x111>(m);
  m = dppmax<0x112>(m);
  m = dppmax<0x114>(m);
  m = dppmax<0x118>(m);
  m = dppmax<0x142>(m);  // row_bcast:15
  m = dppmax<0x143>(m);  // row_bcast:31
  return rdl(m, 63);
}

struct KP {
  const float* tags; const float* lem;
  const float* eWih0; const float* eWhh0; const float* ebih0; const float* ebhh0;
  const float* eWih1; const float* eWhh1; const float* ebih1; const float* ebhh1;
  const float* eWih2; const float* eWhh2; const float* ebih2; const float* ebhh2;
  const float* dWih0; const float* dWhh0; const float* dbih0; const float* dbhh0;
  const float* dWih1; const float* dWhh1; const float* dbih1; const float* dbhh1;
  const float* dWih2; const float* dWhh2; const float* dbih2; const float* dbhh2;
  const float* linW; const float* linb;
  float* outp; float* outt;
  int B;
};

// One wave (64 lanes) per batch chain. 4 chains per 256-thread block. No LDS.
// lane = 4*j + k : lane owns gate row (k*10 + j); k: 0=i, 1=f, 2=g~, 3=o.
// Lanes 40..63 (j>=10) are clamped to j=9 and compute harmless duplicates.
// Dots use v_pk_fma_f32: weights in VGPR pairs, h replicated as SGPR 64-bit
// pairs (best-measured R5 structure). This version software-pipelines each
// step in source: the three self-recurrent partials (pre + whl*hl_old) are
// hoisted to the step top (independent of the serial act/tanh chain), the
// w0c*x term is a single late fma (decoder: layer0 no longer waits on
// argmax), and both loops are unrolled 2x so the scheduler can overlap
// iteration boundaries. Latency-bound diagnosis: ~2.4 resident waves/SIMD x
// (issue 350 / path 420 cyc) = the measured 83% VALUBusy.
__global__ __launch_bounds__(256) void seq2seq_kernel(KP P) {
  const int tid = threadIdx.x;
  const int lane = tid & 63;
  const int b = blockIdx.x * 4 + (tid >> 6);
  if (b >= P.B) return;

  const int jq = lane >> 2;
  const int kg = lane & 3;
  const int jj = (jq < 10) ? jq : 9;
  const int row = kg * 10 + jj;

  // unified activation: sigmoid for i,f,o; tanh (=2*sigmoid(2x)-1) for g~
  const float kc = (kg == 2) ? (-2.0f * LOG2E) : (-LOG2E);
  const float am = (kg == 2) ? 2.0f : 1.0f;
  const float ab = (kg == 2) ? -1.0f : 0.0f;

  auto act = [&](float g) -> float {
    float y = fast_rcp(1.0f + fast_exp2(g * kc));
    return fmaf(am, y, ab);
  };

  // per-chain uniform data
  float tv = (lane < 63) ? P.tags[(size_t)b * 63 + lane] : 0.0f;
  float lemv = (lane < 32) ? P.lem[(size_t)b * 32 + lane] : 0.0f;

  // --- fold the (time-constant) tag contribution into the layer-0 biases ---
  float pre0 = P.ebih0[row] + P.ebhh0[row];
  float dpre0 = P.dbih0[row] + P.dbhh0[row];
  float ew0c, dw0c;
  {
    const float4* e4 = (const float4*)P.eWih0 + row * 16;
    const float4* d4 = (const float4*)P.dWih0 + row * 16;
    float4 we = e4[0], wd = d4[0];
    ew0c = we.x; dw0c = wd.x;
    float t0 = rdl(tv, 0), t1 = rdl(tv, 1), t2 = rdl(tv, 2);
    pre0 = fmaf(we.y, t0, pre0); pre0 = fmaf(we.z, t1, pre0); pre0 = fmaf(we.w, t2, pre0);
    dpre0 = fmaf(wd.y, t0, dpre0); dpre0 = fmaf(wd.z, t1, dpre0); dpre0 = fmaf(wd.w, t2, dpre0);
#pragma unroll
    for (int c = 1; c < 16; c++) {
      float4 e = e4[c], d = d4[c];
      int dd = 4 * c - 1;
      float u0 = rdl(tv, dd), u1 = rdl(tv, dd + 1), u2 = rdl(tv, dd + 2), u3 = rdl(tv, dd + 3);
      pre0 = fmaf(e.x, u0, pre0); pre0 = fmaf(e.y, u1, pre0);
      pre0 = fmaf(e.z, u2, pre0); pre0 = fmaf(e.w, u3, pre0);
      dpre0 = fmaf(d.x, u0, dpre0); dpre0 = fmaf(d.y, u1, dpre0);
      dpre0 = fmaf(d.z, u2, dpre0); dpre0 = fmaf(d.w, u3, dpre0);
    }
  }

  // --- encoder weights as VGPR pairs (lane holds its gate row, 5 v2f each) ---
  v2f ehh0[5], eih1[5], ehh1[5], eih2[5], ehh2[5];
  {
    const v2f* a0 = (const v2f*)(P.eWhh0 + row * 10);
    const v2f* a1 = (const v2f*)(P.eWih1 + row * 10);
    const v2f* a2 = (const v2f*)(P.eWhh1 + row * 10);
    const v2f* a3 = (const v2f*)(P.eWih2 + row * 10);
    const v2f* a4 = (const v2f*)(P.eWhh2 + row * 10);
#pragma unroll
    for (int q = 0; q < 5; q++) {
      ehh0[q] = a0[q]; eih1[q] = a1[q]; ehh1[q] = a2[q];
      eih2[q] = a3[q]; ehh2[q] = a4[q];
    }
  }
  float pre1 = P.ebih1[row] + P.ebhh1[row];
  float pre2 = P.ebih2[row] + P.ebhh2[row];

  // state: h replicated as SGPR pairs {h_{2q}, h_{2q+1}}; c lives per-quad
  uint64_t h0[5], h1[5], h2[5];
#pragma unroll
  for (int q = 0; q < 5; q++) { h0[q] = 0; h1[q] = 0; h2[q] = 0; }
  float c0 = 0.0f, c1 = 0.0f, c2 = 0.0f;

  auto upd = [&](float a, float& c, uint64_t (&h)[5]) {
    float a0 = qb<0>(a);  // sigmoid(i)
    float a1 = qb<1>(a);  // sigmoid(f)
    float a2 = qb<2>(a);  // tanh(g~)
    float a3 = qb<3>(a);  // sigmoid(o)
    c = fmaf(a1, c, a0 * a2);
    // tanh(c) = 2*sigmoid(2c)-1; exp2 over/underflow saturates correctly
    float y = fast_rcp(1.0f + fast_exp2(c * (-2.0f * LOG2E)));
    float hv = a3 * fmaf(2.0f, y, -1.0f);
#pragma unroll
    for (int q = 0; q < 5; q++) h[q] = pack2(rdli(hv, 8 * q), rdli(hv, 8 * q + 4));
  };

  // software-pipelined step: self-recurrent partials first (independent of
  // the serial chain), x folded in with a single late fma.
  auto step = [&](float x, const v2f (&wh0)[5], const v2f (&wi1)[5],
                  const v2f (&wh1)[5], const v2f (&wi2)[5], const v2f (&wh2)[5],
                  float w0c, float p0_, float p1_, float p2_) {
    v2f s0{p0_, 0.0f}, s1{p1_, 0.0f}, s2{p2_, 0.0f};
#pragma unroll
    for (int q = 0; q < 5; q++) {
      pkfma(s0, wh0[q], h0[q]);
      pkfma(s1, wh1[q], h1[q]);
      pkfma(s2, wh2[q], h2[q]);
    }
    upd(act(fmaf(w0c, x, s0.x + s0.y)), c0, h0);

    v2f t1{0.0f, 0.0f};
#pragma unroll
    for (int q = 0; q < 5; q++) pkfma(t1, wi1[q], h0[q]);
    upd(act((s1.x + s1.y) + (t1.x + t1.y)), c1, h1);

    v2f t2{0.0f, 0.0f};
#pragma unroll
    for (int q = 0; q < 5; q++) pkfma(t2, wi2[q], h1[q]);
    upd(act((s2.x + s2.y) + (t2.x + t2.y)), c2, h2);
  };

  // ---------------- encoder: 32 steps ----------------
#pragma unroll 2
  for (int t = 0; t < 32; t++) {
    step(rdl(lemv, t), ehh0, eih1, ehh1, eih2, ehh2, ew0c, pre0, pre1, pre2);
  }

  // --- decoder weights overwrite the same registers (no extra pressure) ---
  {
    const v2f* a0 = (const v2f*)(P.dWhh0 + row * 10);
    const v2f* a1 = (const v2f*)(P.dWih1 + row * 10);
    const v2f* a2 = (const v2f*)(P.dWhh1 + row * 10);
    const v2f* a3 = (const v2f*)(P.dWih2 + row * 10);
    const v2f* a4 = (const v2f*)(P.dWhh2 + row * 10);
#pragma unroll
    for (int q = 0; q < 5; q++) {
      ehh0[q] = a0[q]; eih1[q] = a1[q]; ehh1[q] = a2[q];
      eih2[q] = a3[q]; ehh2[q] = a4[q];
    }
  }
  pre1 = P.dbih1[row] + P.dbhh1[row];
  pre2 = P.dbih2[row] + P.dbhh2[row];

  // linear layer: lane holds rows lane and (64+lane if lane<36), as pairs
  const int lr2 = (lane < 36) ? (64 + lane) : 99;
  v2f lw0[5], lw1[5];
  {
    const v2f* a0 = (const v2f*)(P.linW + lane * 10);
    const v2f* a1 = (const v2f*)(P.linW + lr2 * 10);
#pragma unroll
    for (int q = 0; q < 5; q++) { lw0[q] = a0[q]; lw1[q] = a1[q]; }
  }
  float lb0 = P.linb[lane];
  float lb1 = (lane < 36) ? P.linb[lr2] : -1e30f;

  float* op0 = P.outp + (size_t)b * 3000;
  float tok = 1.0f;   // START
  float tokv = 0.0f;  // lane s accumulates step-s token

  // ---------------- decoder: 30 steps ----------------
#pragma unroll 2
  for (int s = 0; s < 30; s++) {
    step(tok, ehh0, eih1, ehh1, eih2, ehh2, dw0c, dpre0, pre1, pre2);

    // linear + sigmoid (packed dots, hardware exp2/rcp)
    v2f za{lb0, 0.0f}, zb{lb1, 0.0f};
#pragma unroll
    for (int q = 0; q < 5; q++) { pkfma(za, lw0[q], h2[q]); pkfma(zb, lw1[q], h2[q]); }
    float z0 = za.x + za.y, z1 = zb.x + zb.y;
    float p0 = fast_rcp(1.0f + fast_exp2(z0 * (-LOG2E)));
    float p1 = fast_rcp(1.0f + fast_exp2(z1 * (-LOG2E)));  // lanes>=36: exactly 0

    float* op = op0 + s * 100;
    op[lane] = p0;
    if (lane < 36) op[64 + lane] = p1;

    // argmax, first-occurrence: DPP wave-max (VALU) + ballot/ctz (SALU).
    // fmax returns one of its inputs bitwise, so vm matches some p exactly.
    float vm = wavemax_bcast(fmaxf(p0, p1));
    unsigned long long m0 = __ballot(p0 == vm);
    unsigned long long m1 = __ballot(p1 == vm);
    int im = m0 ? (int)__builtin_ctzll(m0) : 64 + (int)__builtin_ctzll(m1);
    tok = (float)im;
    tokv = (lane == s) ? tok : tokv;
  }

  if (lane < 30) P.outt[(size_t)b * 30 + lane] = tokv;
}

extern "C" void kernel_launch(void* const* d_in, const int* in_sizes, int n_in,
                              void* d_out, int out_size, void* d_ws, size_t ws_size,
                              hipStream_t stream) {
  KP P;
  P.tags = (const float*)d_in[2];
  P.lem = (const float*)d_in[3];
  P.eWih0 = (const float*)d_in[4];  P.eWhh0 = (const float*)d_in[5];
  P.ebih0 = (const float*)d_in[6];  P.ebhh0 = (const float*)d_in[7];
  P.eWih1 = (const float*)d_in[8];  P.eWhh1 = (const float*)d_in[9];
  P.ebih1 = (const float*)d_in[10]; P.ebhh1 = (const float*)d_in[11];
  P.eWih2 = (const float*)d_in[12]; P.eWhh2 = (const float*)d_in[13];
  P.ebih2 = (const float*)d_in[14]; P.ebhh2 = (const float*)d_in[15];
  P.dWih0 = (const float*)d_in[16]; P.dWhh0 = (const float*)d_in[17];
  P.dbih0 = (const float*)d_in[18]; P.dbhh0 = (const float*)d_in[19];
  P.dWih1 = (const float*)d_in[20]; P.dWhh1 = (const float*)d_in[21];
  P.dbih1 = (const float*)d_in[22]; P.dbhh1 = (const float*)d_in[23];
  P.dWih2 = (const float*)d_in[24]; P.dWhh2 = (const float*)d_in[25];
  P.dbih2 = (const float*)d_in[26]; P.dbhh2 = (const float*)d_in[27];
  P.linW = (const float*)d_in[28];
  P.linb = (const float*)d_in[29];

  const int B = in_sizes[3] / 32;  // lemmata is (B, 32)
  P.B = B;
  P.outp = (float*)d_out;
  P.outt = P.outp + (size_t)B * 3000;

  const int blocks = (B + 3) / 4;  // 4 chains (waves) per 256-thread block
  seq2seq_kernel<<<dim3(blocks), dim3(256), 0, stream>>>(P);
}